// Round 2
// baseline (319.910 us; speedup 1.0000x reference)
//
#include <hip/hip_runtime.h>
#include <cmath>

// CriticSNN forward: BATCH=65536, STATE_DIM=6, HIDDEN=128, NUM_STEPS=8, OUT=1
// One wave (64 lanes) per batch element; lane l owns neurons l and l+64.
// Spikes are binary -> ballots; matmuls become masked column sums.
//
// v2: zero-LDS variant. Weight matrices (64 KB each) are L2-resident; spike
// masks are sparse, so the bit loops read weights straight from global.
// Dropping the 132 KiB LDS staging doubles the occupancy cap (16 -> 32
// waves/CU), which is the lever for this latency-bound kernel.
// (Resubmission: previous round failed on container acquisition, not kernel.)

constexpr int BATCH = 65536;
constexpr int HID   = 128;
constexpr int SDIM  = 6;
constexpr int NSTEP = 8;
constexpr int BLOCK = 256;                          // 4 waves/block
constexpr int GRID  = 2048;                         // 8 blocks/CU
constexpr int WAVES_TOTAL = GRID * (BLOCK / 64);    // 8192
constexpr int ELEMS_PER_WAVE = BATCH / WAVES_TOTAL; // 8

__global__ __launch_bounds__(BLOCK, 8) void snn_fwd(
    const float* __restrict__ state,
    const float* __restrict__ w_fc1,
    const float* __restrict__ w_rec1,
    const float* __restrict__ w_fc2,
    const float* __restrict__ w_rec2,
    const float* __restrict__ w_mean,
    const float* __restrict__ w_std,
    const float* __restrict__ p_alpha1, const float* __restrict__ p_beta1,
    const float* __restrict__ p_thr1,
    const float* __restrict__ p_alpha2, const float* __restrict__ p_beta2,
    const float* __restrict__ p_thr2,
    float* __restrict__ out)
{
    const int tid   = threadIdx.x;
    const int lane  = tid & 63;
    const int gwave = blockIdx.x * (BLOCK / 64) + (tid >> 6);

    // ---- hoist small weights into registers (per wave, once) ----
    float w1a[SDIM], w1b[SDIM];
    #pragma unroll
    for (int k = 0; k < SDIM; ++k) {
        w1a[k] = w_fc1[lane * SDIM + k];
        w1b[k] = w_fc1[(lane + 64) * SDIM + k];
    }
    const float wm_a = w_mean[lane], wm_b = w_mean[lane + 64];
    const float ws_a = w_std [lane], ws_b = w_std [lane + 64];

    const float a1 = fminf(fmaxf(p_alpha1[0], 0.f), 1.f);
    const float b1 = fminf(fmaxf(p_beta1 [0], 0.f), 1.f);
    const float a2 = fminf(fmaxf(p_alpha2[0], 0.f), 1.f);
    const float b2 = fminf(fmaxf(p_beta2 [0], 0.f), 1.f);
    const float t1 = p_thr1[0];
    const float t2 = p_thr2[0];

    // per-lane weight-row bases (row l and row l+64 of each matrix)
    const float* __restrict__ rec1_a = w_rec1 + lane * HID;
    const float* __restrict__ rec1_b = w_rec1 + (lane + 64) * HID;
    const float* __restrict__ fc2_a  = w_fc2  + lane * HID;
    const float* __restrict__ fc2_b  = w_fc2  + (lane + 64) * HID;
    const float* __restrict__ rec2_a = w_rec2 + lane * HID;
    const float* __restrict__ rec2_b = w_rec2 + (lane + 64) * HID;

    for (int e = 0; e < ELEMS_PER_WAVE; ++e) {
        const int b = gwave + WAVES_TOTAL * e;

        // cur1_in = state[b] @ w_fc1.T  (constant across steps; state loads
        // are wave-uniform -> scalar loads)
        float cur_a = 0.f, cur_b = 0.f;
        #pragma unroll
        for (int k = 0; k < SDIM; ++k) {
            const float s = state[b * SDIM + k];
            cur_a = fmaf(s, w1a[k], cur_a);
            cur_b = fmaf(s, w1b[k], cur_b);
        }

        float syn1a = 0.f, syn1b = 0.f, mem1a = 0.f, mem1b = 0.f;
        float syn2a = 0.f, syn2b = 0.f, mem2a = 0.f, mem2b = 0.f;
        bool  spk1a = false, spk1b = false, spk2a = false, spk2b = false;
        float cnt_a = 0.f, cnt_b = 0.f;
        unsigned long long m1a = 0ull, m1b = 0ull, m2a = 0ull, m2b = 0ull;

        #pragma unroll 1
        for (int t = 0; t < NSTEP; ++t) {
            // ----- layer 1: rec1 contribution from PREVIOUS spk1 -----
            float r_a = 0.f, r_b = 0.f;
            unsigned long long m = m1a;
            while (m) {
                const int j = __builtin_ctzll(m); m &= m - 1;
                r_a += rec1_a[j]; r_b += rec1_b[j];
            }
            m = m1b;
            while (m) {
                const int j = __builtin_ctzll(m) + 64; m &= m - 1;
                r_a += rec1_a[j]; r_b += rec1_b[j];
            }
            syn1a = fmaf(a1, syn1a, cur_a + r_a);
            syn1b = fmaf(a1, syn1b, cur_b + r_b);
            mem1a = fmaf(b1, mem1a, syn1a) - (spk1a ? t1 : 0.f);
            mem1b = fmaf(b1, mem1b, syn1b) - (spk1b ? t1 : 0.f);
            spk1a = (mem1a - t1) > 0.f;
            spk1b = (mem1b - t1) > 0.f;
            m1a = __ballot(spk1a);
            m1b = __ballot(spk1b);

            // ----- layer 2: fc2 from NEW spk1, rec2 from OLD spk2 -----
            float f_a = 0.f, f_b = 0.f;
            m = m1a;
            while (m) {
                const int j = __builtin_ctzll(m); m &= m - 1;
                f_a += fc2_a[j]; f_b += fc2_b[j];
            }
            m = m1b;
            while (m) {
                const int j = __builtin_ctzll(m) + 64; m &= m - 1;
                f_a += fc2_a[j]; f_b += fc2_b[j];
            }
            m = m2a;
            while (m) {
                const int j = __builtin_ctzll(m); m &= m - 1;
                f_a += rec2_a[j]; f_b += rec2_b[j];
            }
            m = m2b;
            while (m) {
                const int j = __builtin_ctzll(m) + 64; m &= m - 1;
                f_a += rec2_a[j]; f_b += rec2_b[j];
            }
            syn2a = fmaf(a2, syn2a, f_a);
            syn2b = fmaf(a2, syn2b, f_b);
            mem2a = fmaf(b2, mem2a, syn2a) - (spk2a ? t2 : 0.f);
            mem2b = fmaf(b2, mem2b, syn2b) - (spk2b ? t2 : 0.f);
            spk2a = (mem2a - t2) > 0.f;
            spk2b = (mem2b - t2) > 0.f;
            m2a = __ballot(spk2a);
            m2b = __ballot(spk2b);
            cnt_a += spk2a ? 1.f : 0.f;
            cnt_b += spk2b ? 1.f : 0.f;
        }

        // ----- head: dot(avg_spikes, w_mean/w_std) + activations -----
        const float avg_a = cnt_a * (1.f / (float)NSTEP);
        const float avg_b = cnt_b * (1.f / (float)NSTEP);
        float dm = avg_a * wm_a + avg_b * wm_b;
        float ds = avg_a * ws_a + avg_b * ws_b;
        #pragma unroll
        for (int off = 32; off > 0; off >>= 1) {
            dm += __shfl_xor(dm, off, 64);
            ds += __shfl_xor(ds, off, 64);
        }
        if (lane == 0) {
            out[b]         = tanhf(dm);
            const float sg = 1.f / (1.f + expf(-(ds + 2.f)));
            out[BATCH + b] = 1.9f * sg + 0.1f;
        }
    }
}

extern "C" void kernel_launch(void* const* d_in, const int* in_sizes, int n_in,
                              void* d_out, int out_size, void* d_ws, size_t ws_size,
                              hipStream_t stream) {
    (void)in_sizes; (void)n_in; (void)d_ws; (void)ws_size; (void)out_size;
    snn_fwd<<<GRID, BLOCK, 0, stream>>>(
        (const float*)d_in[0],  // state
        (const float*)d_in[1],  // w_fc1
        (const float*)d_in[2],  // w_rec1
        (const float*)d_in[3],  // w_fc2
        (const float*)d_in[4],  // w_rec2
        (const float*)d_in[5],  // w_mean
        (const float*)d_in[6],  // w_std
        (const float*)d_in[7],  // alpha1
        (const float*)d_in[8],  // beta1
        (const float*)d_in[9],  // thr1
        (const float*)d_in[10], // alpha2
        (const float*)d_in[11], // beta2
        (const float*)d_in[12], // thr2
        (float*)d_out);
}

// Round 3
// 124.603 us; speedup vs baseline: 2.5674x; 2.5674x over previous
//
#include <hip/hip_runtime.h>
#include <cmath>

// CriticSNN forward: BATCH=65536, STATE_DIM=6, HIDDEN=128, NUM_STEPS=8, OUT=1
// One wave per batch element-PAIR; lane l owns neurons l and l+64 of each.
// Spikes are binary -> ballots; matmuls are masked column sums from LDS.
//
// v3: back to the v1 LDS structure (v2 proved global gathers are 64-line
// catastrophes: VALUBusy 14%). New: 2 elements interleaved per wave for ILP
// (we are LDS-capped at 16 waves/CU, so VGPRs are free), fused fc2(t)+
// rec1(t+1) walks over the same spike mask (half the latency-serial loops,
// 2x loads in flight), hand-rotated bit loops, and state prefetch.

constexpr int BATCH = 65536;
constexpr int HID   = 128;
constexpr int SDIM  = 6;
constexpr int NSTEP = 8;
constexpr int BLOCK = 1024;                         // 16 waves/block
constexpr int GRID  = 256;                          // 1 block per CU
constexpr int WAVES_TOTAL = GRID * (BLOCK / 64);    // 4096
constexpr int ELEMS_PER_WAVE = BATCH / WAVES_TOTAL; // 16
constexpr int PAIRS = ELEMS_PER_WAVE / 2;           // 8

__global__ __launch_bounds__(BLOCK) void snn_fwd(
    const float* __restrict__ state,
    const float* __restrict__ w_fc1,
    const float* __restrict__ w_rec1,
    const float* __restrict__ w_fc2,
    const float* __restrict__ w_rec2,
    const float* __restrict__ w_mean,
    const float* __restrict__ w_std,
    const float* __restrict__ p_alpha1, const float* __restrict__ p_beta1,
    const float* __restrict__ p_thr1,
    const float* __restrict__ p_alpha2, const float* __restrict__ p_beta2,
    const float* __restrict__ p_thr2,
    float* __restrict__ out)
{
    // Packed transposed weights: logical entry (j, l) = float2(w[l][j], w[l+64][j])
    // stored at index j*64 + (l ^ (j & 63)). XOR swizzle: conflict-free b64 reads.
    __shared__ float2 ld_rec1[HID * 64];   // 64 KiB
    __shared__ float2 ld_fc2 [HID * 64];   // 64 KiB

    const int tid = threadIdx.x;

    for (int v = tid; v < HID * 64; v += BLOCK) {
        const int l = v >> 7;        // 0..63
        const int j = v & 127;       // 0..127 (consecutive lanes -> consecutive j)
        const int pos = (j << 6) | (l ^ (j & 63));
        ld_rec1[pos] = make_float2(w_rec1[l * HID + j], w_rec1[(l + 64) * HID + j]);
        ld_fc2 [pos] = make_float2(w_fc2 [l * HID + j], w_fc2 [(l + 64) * HID + j]);
    }

    const int lane  = tid & 63;
    const int gwave = blockIdx.x * (BLOCK / 64) + (tid >> 6);

    // small weights -> registers (read once; L2 absorbs the scatter)
    float w1a[SDIM], w1b[SDIM];
    #pragma unroll
    for (int k = 0; k < SDIM; ++k) {
        w1a[k] = w_fc1[lane * SDIM + k];
        w1b[k] = w_fc1[(lane + 64) * SDIM + k];
    }
    const float wm_a = w_mean[lane], wm_b = w_mean[lane + 64];
    const float ws_a = w_std [lane], ws_b = w_std [lane + 64];

    const float a1 = fminf(fmaxf(p_alpha1[0], 0.f), 1.f);
    const float b1 = fminf(fmaxf(p_beta1 [0], 0.f), 1.f);
    const float a2 = fminf(fmaxf(p_alpha2[0], 0.f), 1.f);
    const float b2 = fminf(fmaxf(p_beta2 [0], 0.f), 1.f);
    const float t1 = p_thr1[0];
    const float t2 = p_thr2[0];

    const float* __restrict__ rec2_a = w_rec2 + lane * HID;
    const float* __restrict__ rec2_b = w_rec2 + (lane + 64) * HID;

    __syncthreads();

    // fused gather: fc2 contribution for THIS step + rec1 contribution for
    // NEXT step, both driven by the same fresh layer-1 spike mask.
    // Hand-rotated: next iteration's loads issue before current accumulate.
    auto walk2 = [&](unsigned long long m, int jbase,
                     float& f_a, float& f_b, float& r_a, float& r_b) {
        if (!m) return;
        int j = __builtin_ctzll(m); m &= m - 1;
        int p = ((j + jbase) << 6) | (lane ^ j);
        float2 wf = ld_fc2[p];
        float2 wr = ld_rec1[p];
        while (m) {
            const int j2 = __builtin_ctzll(m); m &= m - 1;
            const int p2 = ((j2 + jbase) << 6) | (lane ^ j2);
            const float2 wf2 = ld_fc2[p2];
            const float2 wr2 = ld_rec1[p2];
            f_a += wf.x; f_b += wf.y; r_a += wr.x; r_b += wr.y;
            wf = wf2; wr = wr2;
        }
        f_a += wf.x; f_b += wf.y; r_a += wr.x; r_b += wr.y;
    };
    // layer-2 recurrence is almost never active: straight global reads
    auto walkg = [&](unsigned long long m, int jbase, float& f_a, float& f_b) {
        while (m) {
            const int j = __builtin_ctzll(m) + jbase; m &= m - 1;
            f_a += rec2_a[j];
            f_b += rec2_b[j];
        }
    };

    // preload state for pair 0 (wave-uniform -> scalar loads)
    float sx[SDIM], sy[SDIM];
    #pragma unroll
    for (int k = 0; k < SDIM; ++k) {
        sx[k] = state[(gwave) * SDIM + k];
        sy[k] = state[(gwave + WAVES_TOTAL) * SDIM + k];
    }

    for (int e = 0; e < PAIRS; ++e) {
        const int bx = gwave + WAVES_TOTAL * (2 * e);
        const int by = gwave + WAVES_TOTAL * (2 * e + 1);

        // cur1_in = state @ w_fc1.T (constant across steps)
        float curxa = 0.f, curxb = 0.f, curya = 0.f, curyb = 0.f;
        #pragma unroll
        for (int k = 0; k < SDIM; ++k) {
            curxa = fmaf(sx[k], w1a[k], curxa);
            curxb = fmaf(sx[k], w1b[k], curxb);
            curya = fmaf(sy[k], w1a[k], curya);
            curyb = fmaf(sy[k], w1b[k], curyb);
        }

        // prefetch next pair's state; consumed next iteration
        float sxn[SDIM], syn2p[SDIM];
        if (e + 1 < PAIRS) {
            const int bxn = gwave + WAVES_TOTAL * (2 * e + 2);
            const int byn = gwave + WAVES_TOTAL * (2 * e + 3);
            #pragma unroll
            for (int k = 0; k < SDIM; ++k) {
                sxn[k]   = state[bxn * SDIM + k];
                syn2p[k] = state[byn * SDIM + k];
            }
        }

        float s1xa = 0.f, s1xb = 0.f, m1xa = 0.f, m1xb = 0.f;
        float s2xa = 0.f, s2xb = 0.f, m2xa = 0.f, m2xb = 0.f;
        float s1ya = 0.f, s1yb = 0.f, m1ya = 0.f, m1yb = 0.f;
        float s2ya = 0.f, s2yb = 0.f, m2ya = 0.f, m2yb = 0.f;
        bool k1xa = false, k1xb = false, k2xa = false, k2xb = false;
        bool k1ya = false, k1yb = false, k2ya = false, k2yb = false;
        float cxa = 0.f, cxb = 0.f, cya = 0.f, cyb = 0.f;
        unsigned long long M2xa = 0ull, M2xb = 0ull, M2ya = 0ull, M2yb = 0ull;
        float rxa = 0.f, rxb = 0.f, rya = 0.f, ryb = 0.f;   // rec1 contribution

        #pragma unroll 1
        for (int t = 0; t < NSTEP; ++t) {
            // ----- layer 1 (both elements; r* computed last step) -----
            s1xa = fmaf(a1, s1xa, curxa + rxa);
            s1xb = fmaf(a1, s1xb, curxb + rxb);
            s1ya = fmaf(a1, s1ya, curya + rya);
            s1yb = fmaf(a1, s1yb, curyb + ryb);
            m1xa = fmaf(b1, m1xa, s1xa) - (k1xa ? t1 : 0.f);
            m1xb = fmaf(b1, m1xb, s1xb) - (k1xb ? t1 : 0.f);
            m1ya = fmaf(b1, m1ya, s1ya) - (k1ya ? t1 : 0.f);
            m1yb = fmaf(b1, m1yb, s1yb) - (k1yb ? t1 : 0.f);
            k1xa = (m1xa - t1) > 0.f;
            k1xb = (m1xb - t1) > 0.f;
            k1ya = (m1ya - t1) > 0.f;
            k1yb = (m1yb - t1) > 0.f;
            const unsigned long long M1xa = __ballot(k1xa);
            const unsigned long long M1xb = __ballot(k1xb);
            const unsigned long long M1ya = __ballot(k1ya);
            const unsigned long long M1yb = __ballot(k1yb);

            // ----- fused gathers: fc2 (this step) + rec1 (next step) -----
            float fxa = 0.f, fxb = 0.f, fya = 0.f, fyb = 0.f;
            rxa = 0.f; rxb = 0.f; rya = 0.f; ryb = 0.f;
            walk2(M1xa, 0,  fxa, fxb, rxa, rxb);
            walk2(M1ya, 0,  fya, fyb, rya, ryb);
            walk2(M1xb, 64, fxa, fxb, rxa, rxb);
            walk2(M1yb, 64, fya, fyb, rya, ryb);

            // rare layer-2 recurrence
            walkg(M2xa, 0,  fxa, fxb);
            walkg(M2xb, 64, fxa, fxb);
            walkg(M2ya, 0,  fya, fyb);
            walkg(M2yb, 64, fya, fyb);

            // ----- layer 2 (both elements) -----
            s2xa = fmaf(a2, s2xa, fxa);
            s2xb = fmaf(a2, s2xb, fxb);
            s2ya = fmaf(a2, s2ya, fya);
            s2yb = fmaf(a2, s2yb, fyb);
            m2xa = fmaf(b2, m2xa, s2xa) - (k2xa ? t2 : 0.f);
            m2xb = fmaf(b2, m2xb, s2xb) - (k2xb ? t2 : 0.f);
            m2ya = fmaf(b2, m2ya, s2ya) - (k2ya ? t2 : 0.f);
            m2yb = fmaf(b2, m2yb, s2yb) - (k2yb ? t2 : 0.f);
            k2xa = (m2xa - t2) > 0.f;
            k2xb = (m2xb - t2) > 0.f;
            k2ya = (m2ya - t2) > 0.f;
            k2yb = (m2yb - t2) > 0.f;
            M2xa = __ballot(k2xa);
            M2xb = __ballot(k2xb);
            M2ya = __ballot(k2ya);
            M2yb = __ballot(k2yb);
            cxa += k2xa ? 1.f : 0.f;
            cxb += k2xb ? 1.f : 0.f;
            cya += k2ya ? 1.f : 0.f;
            cyb += k2yb ? 1.f : 0.f;
        }

        // ----- head: dot(avg_spikes, w_mean/w_std) + activations -----
        const float axa = cxa * (1.f / (float)NSTEP);
        const float axb = cxb * (1.f / (float)NSTEP);
        const float aya = cya * (1.f / (float)NSTEP);
        const float ayb = cyb * (1.f / (float)NSTEP);
        float dmx = axa * wm_a + axb * wm_b;
        float dsx = axa * ws_a + axb * ws_b;
        float dmy = aya * wm_a + ayb * wm_b;
        float dsy = aya * ws_a + ayb * ws_b;
        #pragma unroll
        for (int off = 32; off > 0; off >>= 1) {
            dmx += __shfl_xor(dmx, off, 64);
            dsx += __shfl_xor(dsx, off, 64);
            dmy += __shfl_xor(dmy, off, 64);
            dsy += __shfl_xor(dsy, off, 64);
        }
        if (lane == 0) {
            out[bx] = tanhf(dmx);
            out[by] = tanhf(dmy);
            const float sgx = 1.f / (1.f + expf(-(dsx + 2.f)));
            const float sgy = 1.f / (1.f + expf(-(dsy + 2.f)));
            out[BATCH + bx] = 1.9f * sgx + 0.1f;
            out[BATCH + by] = 1.9f * sgy + 0.1f;
        }

        if (e + 1 < PAIRS) {
            #pragma unroll
            for (int k = 0; k < SDIM; ++k) { sx[k] = sxn[k]; sy[k] = syn2p[k]; }
        }
    }
}

extern "C" void kernel_launch(void* const* d_in, const int* in_sizes, int n_in,
                              void* d_out, int out_size, void* d_ws, size_t ws_size,
                              hipStream_t stream) {
    (void)in_sizes; (void)n_in; (void)d_ws; (void)ws_size; (void)out_size;
    snn_fwd<<<GRID, BLOCK, 0, stream>>>(
        (const float*)d_in[0],  // state
        (const float*)d_in[1],  // w_fc1
        (const float*)d_in[2],  // w_rec1
        (const float*)d_in[3],  // w_fc2
        (const float*)d_in[4],  // w_rec2
        (const float*)d_in[5],  // w_mean
        (const float*)d_in[6],  // w_std
        (const float*)d_in[7],  // alpha1
        (const float*)d_in[8],  // beta1
        (const float*)d_in[9],  // thr1
        (const float*)d_in[10], // alpha2
        (const float*)d_in[11], // beta2
        (const float*)d_in[12], // thr2
        (float*)d_out);
}

// Round 4
// 122.367 us; speedup vs baseline: 2.6144x; 1.0183x over previous
//
#include <hip/hip_runtime.h>
#include <cmath>

// CriticSNN forward: BATCH=65536, STATE_DIM=6, HIDDEN=128, NUM_STEPS=8, OUT=1
// One wave per batch element-PAIR; lane l owns neurons l and l+64 of each.
// Spikes are binary -> ballots; matmuls are masked column sums from LDS.
//
// v4: instruction-count surgery on the bit-walk loops (the VALU hog per
// rocprof: ~155 VALU/step-iter at 60% busy).
//  - ONE float4 LDS table {rec1[l][j], rec1[l+64][j], fc2[l][j], fc2[l+64][j]}
//    at the swizzled slot -> one ds_read_b128 + one addr calc per set bit
//    (was 2x ds_read_b64 + 2x addr).
//  - packed-f32 accumulators (ext_vector_type(2)) -> v_pk_add/v_pk_fma halve
//    the scalar adds in the walks and the neuron-update chain. Same IEEE ops
//    in the same order: bit-exact vs v3.
//  - rec2 loops guarded by one combined-mask test (layer-2 spikes ~never).

typedef float f32x2 __attribute__((ext_vector_type(2)));
typedef float f32x4 __attribute__((ext_vector_type(4)));

constexpr int BATCH = 65536;
constexpr int HID   = 128;
constexpr int SDIM  = 6;
constexpr int NSTEP = 8;
constexpr int BLOCK = 1024;                         // 16 waves/block
constexpr int GRID  = 256;                          // 1 block per CU
constexpr int WAVES_TOTAL = GRID * (BLOCK / 64);    // 4096
constexpr int ELEMS_PER_WAVE = BATCH / WAVES_TOTAL; // 16
constexpr int PAIRS = ELEMS_PER_WAVE / 2;           // 8

__global__ __launch_bounds__(BLOCK) void snn_fwd(
    const float* __restrict__ state,
    const float* __restrict__ w_fc1,
    const float* __restrict__ w_rec1,
    const float* __restrict__ w_fc2,
    const float* __restrict__ w_rec2,
    const float* __restrict__ w_mean,
    const float* __restrict__ w_std,
    const float* __restrict__ p_alpha1, const float* __restrict__ p_beta1,
    const float* __restrict__ p_thr1,
    const float* __restrict__ p_alpha2, const float* __restrict__ p_beta2,
    const float* __restrict__ p_thr2,
    float* __restrict__ out)
{
    // entry (j, l) at index j*64 + (l ^ (j & 63)); XOR swizzle keeps both the
    // staging ds_write_b128 and the uniform-j gather ds_read_b128 conflict-free.
    __shared__ f32x4 ldw[HID * 64];   // 128 KiB

    const int tid = threadIdx.x;

    for (int v = tid; v < HID * 64; v += BLOCK) {
        const int l = v >> 7;        // 0..63
        const int j = v & 127;       // 0..127 (consecutive lanes -> consecutive j)
        const int pos = (j << 6) | (l ^ (j & 63));
        f32x4 w;
        w.x = w_rec1[l * HID + j];
        w.y = w_rec1[(l + 64) * HID + j];
        w.z = w_fc2 [l * HID + j];
        w.w = w_fc2 [(l + 64) * HID + j];
        ldw[pos] = w;
    }

    const int lane  = tid & 63;
    const int gwave = blockIdx.x * (BLOCK / 64) + (tid >> 6);

    // small weights -> registers
    f32x2 w1[SDIM];
    #pragma unroll
    for (int k = 0; k < SDIM; ++k) {
        w1[k].x = w_fc1[lane * SDIM + k];
        w1[k].y = w_fc1[(lane + 64) * SDIM + k];
    }
    const float wm_a = w_mean[lane], wm_b = w_mean[lane + 64];
    const float ws_a = w_std [lane], ws_b = w_std [lane + 64];

    const float a1 = fminf(fmaxf(p_alpha1[0], 0.f), 1.f);
    const float b1 = fminf(fmaxf(p_beta1 [0], 0.f), 1.f);
    const float a2 = fminf(fmaxf(p_alpha2[0], 0.f), 1.f);
    const float b2 = fminf(fmaxf(p_beta2 [0], 0.f), 1.f);
    const float t1 = p_thr1[0];
    const float t2 = p_thr2[0];
    const f32x2 a1v = {a1, a1}, b1v = {b1, b1}, a2v = {a2, a2}, b2v = {b2, b2};

    const float* __restrict__ rec2_a = w_rec2 + lane * HID;
    const float* __restrict__ rec2_b = w_rec2 + (lane + 64) * HID;

    __syncthreads();

    // fused gather over one spike mask: rec1 (next step) into r, fc2 (this
    // step) into f. One ds_read_b128 per set bit; hand-rotated so the next
    // load issues before the current accumulate.
    auto walk2 = [&](unsigned long long m, const f32x4* __restrict__ base,
                     f32x2& f, f32x2& r) {
        if (!m) return;
        int j = __builtin_ctzll(m); m &= m - 1;
        f32x4 w = base[(j << 6) | (lane ^ j)];
        while (m) {
            const int j2 = __builtin_ctzll(m); m &= m - 1;
            const f32x4 w2 = base[(j2 << 6) | (lane ^ j2)];
            r += __builtin_shufflevector(w, w, 0, 1);
            f += __builtin_shufflevector(w, w, 2, 3);
            w = w2;
        }
        r += __builtin_shufflevector(w, w, 0, 1);
        f += __builtin_shufflevector(w, w, 2, 3);
    };
    // layer-2 recurrence is almost never active: straight global reads
    auto walkg = [&](unsigned long long m, int jbase, f32x2& f) {
        while (m) {
            const int j = __builtin_ctzll(m) + jbase; m &= m - 1;
            f.x += rec2_a[j];
            f.y += rec2_b[j];
        }
    };

    const f32x4* __restrict__ baseLo = ldw;
    const f32x4* __restrict__ baseHi = ldw + (64 << 6);

    // preload state for pair 0 (wave-uniform -> scalar loads)
    float sx[SDIM], sy[SDIM];
    #pragma unroll
    for (int k = 0; k < SDIM; ++k) {
        sx[k] = state[(gwave) * SDIM + k];
        sy[k] = state[(gwave + WAVES_TOTAL) * SDIM + k];
    }

    for (int e = 0; e < PAIRS; ++e) {
        const int bx = gwave + WAVES_TOTAL * (2 * e);
        const int by = gwave + WAVES_TOTAL * (2 * e + 1);

        // cur1_in = state @ w_fc1.T (constant across steps)
        f32x2 curx = {0.f, 0.f}, cury = {0.f, 0.f};
        #pragma unroll
        for (int k = 0; k < SDIM; ++k) {
            const f32x2 sxv = {sx[k], sx[k]};
            const f32x2 syv = {sy[k], sy[k]};
            curx = __builtin_elementwise_fma(sxv, w1[k], curx);
            cury = __builtin_elementwise_fma(syv, w1[k], cury);
        }

        // prefetch next pair's state; consumed next iteration
        float sxn[SDIM], syn2p[SDIM];
        if (e + 1 < PAIRS) {
            const int bxn = gwave + WAVES_TOTAL * (2 * e + 2);
            const int byn = gwave + WAVES_TOTAL * (2 * e + 3);
            #pragma unroll
            for (int k = 0; k < SDIM; ++k) {
                sxn[k]   = state[bxn * SDIM + k];
                syn2p[k] = state[byn * SDIM + k];
            }
        }

        f32x2 s1x = {0.f, 0.f}, m1x = {0.f, 0.f}, s2x = {0.f, 0.f}, m2x = {0.f, 0.f};
        f32x2 s1y = {0.f, 0.f}, m1y = {0.f, 0.f}, s2y = {0.f, 0.f}, m2y = {0.f, 0.f};
        bool k1xa = false, k1xb = false, k2xa = false, k2xb = false;
        bool k1ya = false, k1yb = false, k2ya = false, k2yb = false;
        f32x2 cx = {0.f, 0.f}, cy = {0.f, 0.f};
        unsigned long long M2xa = 0ull, M2xb = 0ull, M2ya = 0ull, M2yb = 0ull;
        f32x2 rx = {0.f, 0.f}, ry = {0.f, 0.f};   // rec1 contribution (from prev step)

        #pragma unroll 1
        for (int t = 0; t < NSTEP; ++t) {
            // ----- layer 1 (both elements; r* computed last step) -----
            s1x = __builtin_elementwise_fma(a1v, s1x, curx + rx);
            s1y = __builtin_elementwise_fma(a1v, s1y, cury + ry);
            const f32x2 rst1x = {k1xa ? t1 : 0.f, k1xb ? t1 : 0.f};
            const f32x2 rst1y = {k1ya ? t1 : 0.f, k1yb ? t1 : 0.f};
            m1x = __builtin_elementwise_fma(b1v, m1x, s1x) - rst1x;
            m1y = __builtin_elementwise_fma(b1v, m1y, s1y) - rst1y;
            k1xa = (m1x.x - t1) > 0.f;
            k1xb = (m1x.y - t1) > 0.f;
            k1ya = (m1y.x - t1) > 0.f;
            k1yb = (m1y.y - t1) > 0.f;
            const unsigned long long M1xa = __ballot(k1xa);
            const unsigned long long M1xb = __ballot(k1xb);
            const unsigned long long M1ya = __ballot(k1ya);
            const unsigned long long M1yb = __ballot(k1yb);

            // ----- fused gathers: fc2 (this step) + rec1 (next step) -----
            f32x2 fx = {0.f, 0.f}, fy = {0.f, 0.f};
            rx = (f32x2){0.f, 0.f}; ry = (f32x2){0.f, 0.f};
            walk2(M1xa, baseLo, fx, rx);
            walk2(M1ya, baseLo, fy, ry);
            walk2(M1xb, baseHi, fx, rx);
            walk2(M1yb, baseHi, fy, ry);

            // rare layer-2 recurrence (usually all-zero -> one test)
            if ((M2xa | M2xb | M2ya | M2yb) != 0ull) {
                walkg(M2xa, 0,  fx);
                walkg(M2xb, 64, fx);
                walkg(M2ya, 0,  fy);
                walkg(M2yb, 64, fy);
            }

            // ----- layer 2 (both elements) -----
            s2x = __builtin_elementwise_fma(a2v, s2x, fx);
            s2y = __builtin_elementwise_fma(a2v, s2y, fy);
            const f32x2 rst2x = {k2xa ? t2 : 0.f, k2xb ? t2 : 0.f};
            const f32x2 rst2y = {k2ya ? t2 : 0.f, k2yb ? t2 : 0.f};
            m2x = __builtin_elementwise_fma(b2v, m2x, s2x) - rst2x;
            m2y = __builtin_elementwise_fma(b2v, m2y, s2y) - rst2y;
            k2xa = (m2x.x - t2) > 0.f;
            k2xb = (m2x.y - t2) > 0.f;
            k2ya = (m2y.x - t2) > 0.f;
            k2yb = (m2y.y - t2) > 0.f;
            M2xa = __ballot(k2xa);
            M2xb = __ballot(k2xb);
            M2ya = __ballot(k2ya);
            M2yb = __ballot(k2yb);
            const f32x2 onex = {k2xa ? 1.f : 0.f, k2xb ? 1.f : 0.f};
            const f32x2 oney = {k2ya ? 1.f : 0.f, k2yb ? 1.f : 0.f};
            cx += onex;
            cy += oney;
        }

        // ----- head: dot(avg_spikes, w_mean/w_std) + activations -----
        const float axa = cx.x * (1.f / (float)NSTEP);
        const float axb = cx.y * (1.f / (float)NSTEP);
        const float aya = cy.x * (1.f / (float)NSTEP);
        const float ayb = cy.y * (1.f / (float)NSTEP);
        float dmx = axa * wm_a + axb * wm_b;
        float dsx = axa * ws_a + axb * ws_b;
        float dmy = aya * wm_a + ayb * wm_b;
        float dsy = aya * ws_a + ayb * ws_b;
        #pragma unroll
        for (int off = 32; off > 0; off >>= 1) {
            dmx += __shfl_xor(dmx, off, 64);
            dsx += __shfl_xor(dsx, off, 64);
            dmy += __shfl_xor(dmy, off, 64);
            dsy += __shfl_xor(dsy, off, 64);
        }
        if (lane == 0) {
            out[bx] = tanhf(dmx);
            out[by] = tanhf(dmy);
            const float sgx = 1.f / (1.f + expf(-(dsx + 2.f)));
            const float sgy = 1.f / (1.f + expf(-(dsy + 2.f)));
            out[BATCH + bx] = 1.9f * sgx + 0.1f;
            out[BATCH + by] = 1.9f * sgy + 0.1f;
        }

        if (e + 1 < PAIRS) {
            #pragma unroll
            for (int k = 0; k < SDIM; ++k) { sx[k] = sxn[k]; sy[k] = syn2p[k]; }
        }
    }
}

extern "C" void kernel_launch(void* const* d_in, const int* in_sizes, int n_in,
                              void* d_out, int out_size, void* d_ws, size_t ws_size,
                              hipStream_t stream) {
    (void)in_sizes; (void)n_in; (void)d_ws; (void)ws_size; (void)out_size;
    snn_fwd<<<GRID, BLOCK, 0, stream>>>(
        (const float*)d_in[0],  // state
        (const float*)d_in[1],  // w_fc1
        (const float*)d_in[2],  // w_rec1
        (const float*)d_in[3],  // w_fc2
        (const float*)d_in[4],  // w_rec2
        (const float*)d_in[5],  // w_mean
        (const float*)d_in[6],  // w_std
        (const float*)d_in[7],  // alpha1
        (const float*)d_in[8],  // beta1
        (const float*)d_in[9],  // thr1
        (const float*)d_in[10], // alpha2
        (const float*)d_in[11], // beta2
        (const float*)d_in[12], // thr2
        (float*)d_out);
}